// Round 1
// baseline (784.987 us; speedup 1.0000x reference)
//
#include <hip/hip_runtime.h>

#define NN 50000
#define NE 800000
#define F 128
#define NREL 4
#define TR 32      // rows per block tile
#define KH 64      // K half (split W into two 32KB LDS loads)
#define BN_EPS 1e-5f

// ---------------- scatter: agg[rel, dst, :] += x[src, :] ----------------
__global__ __launch_bounds__(256) void scatter_kernel(
    const float* __restrict__ x, const int* __restrict__ ei,
    const int* __restrict__ et, float* __restrict__ agg)
{
    long idx = (long)blockIdx.x * 256 + threadIdx.x;
    int e = (int)(idx >> 7);
    if (e >= NE) return;
    int f = (int)(idx & 127);
    int src = ei[e];
    int dst = ei[NE + e];
    int rel = et[e];
    atomicAdd(&agg[((size_t)rel * NN + dst) * F + f], x[(size_t)src * F + f]);
}

// ------------- GEMM1: hbuf = (x + hbuf) @ W1[r] + b1[r], in-place -------------
// also accumulates per-(rel, col) sum and sumsq for BatchNorm
__global__ __launch_bounds__(256) void gemm1_kernel(
    const float* __restrict__ x, const float* __restrict__ W1,
    const float* __restrict__ b1, float* __restrict__ hbuf,
    float* __restrict__ sums, float* __restrict__ sumsq)
{
    __shared__ float Wl[KH * F];   // 32 KB
    __shared__ float ht[TR * F];   // 16 KB
    __shared__ float csum[F], csq[F];

    const int tid = threadIdx.x;
    const int r = blockIdx.y;
    const int n0 = blockIdx.x * TR;
    const int tx = tid & 31, ty = tid >> 5;
    const int c0 = tx * 4, r0 = ty * 4;

    float acc[4][4];
    #pragma unroll
    for (int j = 0; j < 4; j++) {
        float bv = b1[r * F + c0 + j];
        #pragma unroll
        for (int i = 0; i < 4; i++) acc[i][j] = bv;
    }
    if (tid < F) { csum[tid] = 0.f; csq[tid] = 0.f; }

    const float* Wg = W1 + (size_t)r * F * F;
    const size_t hbase = ((size_t)r * NN + n0) * F;

    for (int kh = 0; kh < 2; kh++) {
        __syncthreads();
        if (kh == 0) {
            #pragma unroll
            for (int p = 0; p < 4; p++) {
                int i = tid * 4 + p * 1024;
                int row = i >> 7;
                float4 v = make_float4(0.f, 0.f, 0.f, 0.f);
                if (n0 + row < NN) {
                    float4 a = *(const float4*)&hbuf[hbase + i];
                    float4 b = *(const float4*)&x[(size_t)(n0 + row) * F + (i & 127)];
                    v = make_float4(a.x + b.x, a.y + b.y, a.z + b.z, a.w + b.w);
                }
                *(float4*)&ht[i] = v;
            }
        }
        #pragma unroll
        for (int p = 0; p < 8; p++) {
            int i = tid * 4 + p * 1024;
            *(float4*)&Wl[i] = *(const float4*)&Wg[kh * KH * F + i];
        }
        __syncthreads();
        #pragma unroll 2
        for (int k2 = 0; k2 < KH; k2++) {
            float4 wv = *(float4*)&Wl[k2 * F + c0];
            int k = kh * KH + k2;
            #pragma unroll
            for (int i = 0; i < 4; i++) {
                float hv = ht[(r0 + i) * F + k];
                acc[i][0] += hv * wv.x;
                acc[i][1] += hv * wv.y;
                acc[i][2] += hv * wv.z;
                acc[i][3] += hv * wv.w;
            }
        }
    }

    #pragma unroll
    for (int i = 0; i < 4; i++) {
        int n = n0 + r0 + i;
        if (n < NN) {
            float4 v = make_float4(acc[i][0], acc[i][1], acc[i][2], acc[i][3]);
            *(float4*)&hbuf[((size_t)r * NN + n) * F + c0] = v;
        }
    }
    #pragma unroll
    for (int j = 0; j < 4; j++) {
        float ls = 0.f, lq = 0.f;
        #pragma unroll
        for (int i = 0; i < 4; i++) {
            if (n0 + r0 + i < NN) { float v = acc[i][j]; ls += v; lq += v * v; }
        }
        atomicAdd(&csum[c0 + j], ls);
        atomicAdd(&csq[c0 + j], lq);
    }
    __syncthreads();
    if (tid < F) {
        atomicAdd(&sums[r * F + tid], csum[tid]);
        atomicAdd(&sumsq[r * F + tid], csq[tid]);
    }
}

// ------------- GEMM2: out = x@Wself + bself + sum_r relu(bn(h1_r))@W2[r] + b2[r] -------------
__global__ __launch_bounds__(256) void gemm2_kernel(
    const float* __restrict__ x, const float* __restrict__ hbuf,
    const float* __restrict__ W2, const float* __restrict__ b2,
    const float* __restrict__ Wself, const float* __restrict__ bself,
    const float* __restrict__ gamma, const float* __restrict__ beta,
    const float* __restrict__ sums, const float* __restrict__ sumsq,
    float* __restrict__ out)
{
    __shared__ float Wl[KH * F];   // 32 KB
    __shared__ float ht[TR * F];   // 16 KB

    const int tid = threadIdx.x;
    const int n0 = blockIdx.x * TR;
    const int tx = tid & 31, ty = tid >> 5;
    const int c0 = tx * 4, r0 = ty * 4;

    float acc[4][4] = {};
    const int kb = (tid * 4) & 127;   // this thread's fixed k positions when staging

    for (int rel = 0; rel < 5; rel++) {
        const float* Wg = (rel < 4) ? (W2 + (size_t)rel * F * F) : Wself;
        float a0[4] = {0.f, 0.f, 0.f, 0.f};
        float b0[4] = {0.f, 0.f, 0.f, 0.f};
        if (rel < 4) {
            #pragma unroll
            for (int j = 0; j < 4; j++) {
                int k = kb + j;
                float mean = sums[rel * F + k] * (1.0f / NN);
                float var = sumsq[rel * F + k] * (1.0f / NN) - mean * mean;
                float g = gamma[rel * F + k] * rsqrtf(var + BN_EPS);
                a0[j] = g;
                b0[j] = beta[rel * F + k] - mean * g;
            }
        }
        for (int kh = 0; kh < 2; kh++) {
            __syncthreads();   // prior readers of Wl/ht done
            if (kh == 0) {
                #pragma unroll
                for (int p = 0; p < 4; p++) {
                    int i = tid * 4 + p * 1024;
                    int row = i >> 7;
                    float4 v = make_float4(0.f, 0.f, 0.f, 0.f);
                    if (n0 + row < NN) {
                        if (rel < 4) {
                            float4 hv = *(const float4*)&hbuf[((size_t)rel * NN + n0) * F + i];
                            v.x = fmaxf(fmaf(hv.x, a0[0], b0[0]), 0.f);
                            v.y = fmaxf(fmaf(hv.y, a0[1], b0[1]), 0.f);
                            v.z = fmaxf(fmaf(hv.z, a0[2], b0[2]), 0.f);
                            v.w = fmaxf(fmaf(hv.w, a0[3], b0[3]), 0.f);
                        } else {
                            v = *(const float4*)&x[(size_t)(n0 + row) * F + (i & 127)];
                        }
                    }
                    *(float4*)&ht[i] = v;
                }
            }
            #pragma unroll
            for (int p = 0; p < 8; p++) {
                int i = tid * 4 + p * 1024;
                *(float4*)&Wl[i] = *(const float4*)&Wg[kh * KH * F + i];
            }
            __syncthreads();
            #pragma unroll 2
            for (int k2 = 0; k2 < KH; k2++) {
                float4 wv = *(float4*)&Wl[k2 * F + c0];
                int k = kh * KH + k2;
                #pragma unroll
                for (int i = 0; i < 4; i++) {
                    float hv = ht[(r0 + i) * F + k];
                    acc[i][0] += hv * wv.x;
                    acc[i][1] += hv * wv.y;
                    acc[i][2] += hv * wv.z;
                    acc[i][3] += hv * wv.w;
                }
            }
        }
    }

    float bias[4];
    #pragma unroll
    for (int j = 0; j < 4; j++) {
        float b = bself[c0 + j];
        #pragma unroll
        for (int rel = 0; rel < 4; rel++) b += b2[rel * F + c0 + j];
        bias[j] = b;
    }
    #pragma unroll
    for (int i = 0; i < 4; i++) {
        int n = n0 + r0 + i;
        if (n < NN) {
            float4 v = make_float4(acc[i][0] + bias[0], acc[i][1] + bias[1],
                                   acc[i][2] + bias[2], acc[i][3] + bias[3]);
            *(float4*)&out[(size_t)n * F + c0] = v;
        }
    }
}

extern "C" void kernel_launch(void* const* d_in, const int* in_sizes, int n_in,
                              void* d_out, int out_size, void* d_ws, size_t ws_size,
                              hipStream_t stream) {
    const float* x     = (const float*)d_in[0];
    const int*   ei    = (const int*)d_in[1];
    const int*   et    = (const int*)d_in[2];
    const float* Wself = (const float*)d_in[3];
    const float* bself = (const float*)d_in[4];
    const float* W1    = (const float*)d_in[5];
    const float* b1    = (const float*)d_in[6];
    const float* gamma = (const float*)d_in[7];
    const float* beta  = (const float*)d_in[8];
    const float* W2    = (const float*)d_in[9];
    const float* b2    = (const float*)d_in[10];
    float* out = (float*)d_out;

    float* hbuf = (float*)d_ws;                       // [NREL, NN, F] agg -> h1 (in-place)
    size_t hbuf_elems = (size_t)NREL * NN * F;
    float* sums  = hbuf + hbuf_elems;                 // [NREL, F]
    float* sumsq = sums + NREL * F;                   // [NREL, F]

    hipMemsetAsync(d_ws, 0, (hbuf_elems + 2 * (size_t)NREL * F) * sizeof(float), stream);

    {
        long total = (long)NE * F;
        int grid = (int)((total + 255) / 256);
        scatter_kernel<<<grid, 256, 0, stream>>>(x, ei, et, hbuf);
    }
    {
        dim3 grid((NN + TR - 1) / TR, NREL);
        gemm1_kernel<<<grid, 256, 0, stream>>>(x, W1, b1, hbuf, sums, sumsq);
    }
    {
        int grid = (NN + TR - 1) / TR;
        gemm2_kernel<<<grid, 256, 0, stream>>>(x, hbuf, W2, b2, Wself, bself,
                                               gamma, beta, sums, sumsq, out);
    }
}

// Round 3
// 590.776 us; speedup vs baseline: 1.3287x; 1.3287x over previous
//
#include <hip/hip_runtime.h>

#define NN 50000
#define NE 800000
#define F 128
#define NREL 4
#define BN_EPS 1e-5f
#define ROWS 64          // rows per block tile
#define LDW 136          // padded LDS row stride in bf16 elems (+16B kills bank conflicts)

typedef __attribute__((ext_vector_type(8))) short short8;
typedef __attribute__((ext_vector_type(4))) float floatx4;

__device__ __forceinline__ ushort f2bf(float f) {
    union { float f; unsigned u; } v; v.f = f;
    unsigned r = v.u + 0x7fffu + ((v.u >> 16) & 1u);
    return (ushort)(r >> 16);
}
__device__ __forceinline__ float bf2f(ushort h) {
    union { unsigned u; float f; } v; v.u = ((unsigned)h) << 16;
    return v.f;
}

// ---------------- scatter: agg[rel, dst, :] += x[src, :] ----------------
__global__ __launch_bounds__(256) void scatter_kernel(
    const float* __restrict__ x, const int* __restrict__ ei,
    const int* __restrict__ et, float* __restrict__ agg)
{
    long idx = (long)blockIdx.x * 256 + threadIdx.x;
    int e = (int)(idx >> 7);
    if (e >= NE) return;
    int f = (int)(idx & 127);
    int src = ei[e];
    int dst = ei[NE + e];
    int rel = et[e];
    atomicAdd(&agg[((size_t)rel * NN + dst) * F + f], x[(size_t)src * F + f]);
}

// ---------------- prep: weights -> bf16 transposed Wt_g[mat][n][k] ----------------
// mats 0..3 = W1[r], 4..7 = W2[r], 8 = Wself
__global__ __launch_bounds__(256) void prep_kernel(
    const float* __restrict__ W1, const float* __restrict__ W2,
    const float* __restrict__ Wself, ushort* __restrict__ Wt_g)
{
    __shared__ ushort Lt[F * F];   // 32 KB
    int m = blockIdx.x;
    const float* src = (m < 4) ? (W1 + (size_t)m * F * F)
                     : (m < 8) ? (W2 + (size_t)(m - 4) * F * F)
                               : Wself;
    int tid = threadIdx.x;
    #pragma unroll
    for (int p = 0; p < 16; p++) {          // 4096 float4 total
        int i4 = tid + p * 256;
        int k = i4 >> 5;                    // 32 float4 per k-row
        int n4 = (i4 & 31) * 4;
        float4 v = *(const float4*)(src + (size_t)k * F + n4);
        Lt[(n4 + 0) * F + k] = f2bf(v.x);
        Lt[(n4 + 1) * F + k] = f2bf(v.y);
        Lt[(n4 + 2) * F + k] = f2bf(v.z);
        Lt[(n4 + 3) * F + k] = f2bf(v.w);
    }
    __syncthreads();
    #pragma unroll
    for (int p = 0; p < 8; p++) {           // 2048 16B chunks, contiguous
        int c = tid + p * 256;
        *(uint4*)(Wt_g + (size_t)m * F * F + c * 8) = *(const uint4*)&Lt[c * 8];
    }
}

// ---------------- GEMM1: h1 = bf16((x+agg) @ W1[r] + b1[r]), BN stats ----------------
__global__ __launch_bounds__(256) void gemm1_kernel(
    const float* __restrict__ x, const ushort* __restrict__ Wt_g,
    const float* __restrict__ b1, float* __restrict__ agg,
    float* __restrict__ sums, float* __restrict__ sumsq)
{
    __shared__ __attribute__((aligned(16))) ushort At[ROWS * LDW];  // 17 KB
    __shared__ __attribute__((aligned(16))) ushort Wt[F * LDW];     // 34.8 KB
    __shared__ float csum[F], csq[F];

    const int tid = threadIdx.x;
    const int r = blockIdx.y;
    const int n0 = blockIdx.x * ROWS;

    if (tid < F) { csum[tid] = 0.f; csq[tid] = 0.f; }

    // stage A = bf16(x + agg)  (64 x 128)
    const float* aggr = agg + ((size_t)r * NN + n0) * F;
    #pragma unroll
    for (int p = 0; p < 8; p++) {
        int i4 = tid + p * 256;             // 2048 float4: 64 rows x 32
        int row = i4 >> 5;
        int c4 = (i4 & 31) * 4;
        unsigned lo = 0, hi = 0;
        if (n0 + row < NN) {
            float4 a = *(const float4*)(aggr + (size_t)row * F + c4);
            float4 b = *(const float4*)(x + (size_t)(n0 + row) * F + c4);
            lo = (unsigned)f2bf(a.x + b.x) | ((unsigned)f2bf(a.y + b.y) << 16);
            hi = (unsigned)f2bf(a.z + b.z) | ((unsigned)f2bf(a.w + b.w) << 16);
        }
        *(uint2*)&At[row * LDW + c4] = make_uint2(lo, hi);
    }
    // stage Wt (bf16 [n][k]) : 128 rows x 16 chunks of 8 ushorts
    {
        const ushort* wg = Wt_g + (size_t)r * F * F;
        #pragma unroll
        for (int p = 0; p < 8; p++) {
            int c = tid + p * 256;          // 2048 chunks
            int n = c >> 4, off = (c & 15) * 8;
            *(uint4*)&Wt[n * LDW + off] = *(const uint4*)(wg + c * 8);
        }
    }
    __syncthreads();

    const int lane = tid & 63, w = tid >> 6;
    const int m = lane & 15, quad = lane >> 4;
    const int rb = w * 16;
    floatx4 acc[8];
    #pragma unroll
    for (int g = 0; g < 8; g++) acc[g] = (floatx4)0.f;

    const ushort* Ap = &At[(rb + m) * LDW + quad * 8];
    const ushort* Bp = &Wt[m * LDW + quad * 8];
    #pragma unroll
    for (int kk = 0; kk < 4; kk++) {
        short8 a = *(const short8*)(Ap + kk * 32);
        #pragma unroll
        for (int g = 0; g < 8; g++) {
            short8 b = *(const short8*)(Bp + g * 16 * LDW + kk * 32);
            acc[g] = __builtin_amdgcn_mfma_f32_16x16x32_bf16(a, b, acc[g], 0, 0, 0);
        }
    }
    __syncthreads();   // all waves done reading At/Wt

    // epilogue: bias, BN partial sums, bf16 result into At (stride LDW)
    #pragma unroll
    for (int g = 0; g < 8; g++) {
        int c = g * 16 + m;
        float bv = b1[r * F + c];
        float ls = 0.f, lq = 0.f;
        #pragma unroll
        for (int i = 0; i < 4; i++) {
            int lrow = rb + quad * 4 + i;
            float v = acc[g][i] + bv;
            At[lrow * LDW + c] = f2bf(v);
            if (n0 + lrow < NN) { ls += v; lq += v * v; }
        }
        atomicAdd(&csum[c], ls);
        atomicAdd(&csq[c], lq);
    }
    __syncthreads();

    // h1 bf16 stored in-place in first 256B of each 512B agg row
    // 64 rows x 16 chunks of 8 ushorts = 1024 chunks
    ushort* h1 = (ushort*)agg;
    #pragma unroll
    for (int p = 0; p < 4; p++) {
        int c = tid + p * 256;
        int row = c >> 4, off = (c & 15) * 8;
        if (n0 + row < NN)
            *(uint4*)(h1 + ((size_t)r * NN + n0 + row) * 256 + off) =
                *(const uint4*)&At[row * LDW + off];
    }
    if (tid < F) {
        atomicAdd(&sums[r * F + tid], csum[tid]);
        atomicAdd(&sumsq[r * F + tid], csq[tid]);
    }
}

// ------- GEMM2: out = x@Wself + bself + sum_r relu(bn(h1_r))@W2[r] + b2[r] -------
__global__ __launch_bounds__(256) void gemm2_kernel(
    const float* __restrict__ x, const float* __restrict__ agg,
    const ushort* __restrict__ Wt_g,
    const float* __restrict__ b2, const float* __restrict__ bself,
    const float* __restrict__ gamma, const float* __restrict__ beta,
    const float* __restrict__ sums, const float* __restrict__ sumsq,
    float* __restrict__ out)
{
    __shared__ __attribute__((aligned(16))) ushort At[ROWS * LDW];
    __shared__ __attribute__((aligned(16))) ushort Wt[F * LDW];
    __shared__ float sA[NREL][F], sB[NREL][F];

    const int tid = threadIdx.x;
    const int n0 = blockIdx.x * ROWS;

    if (tid < F) {
        #pragma unroll
        for (int r = 0; r < NREL; r++) {
            float mean = sums[r * F + tid] * (1.0f / NN);
            float var = sumsq[r * F + tid] * (1.0f / NN) - mean * mean;
            float g = gamma[r * F + tid] * rsqrtf(var + BN_EPS);
            sA[r][tid] = g;
            sB[r][tid] = beta[r * F + tid] - mean * g;
        }
    }

    const int lane = tid & 63, w = tid >> 6;
    const int m = lane & 15, quad = lane >> 4;
    const int rb = w * 16;
    floatx4 acc[8];
    #pragma unroll
    for (int g = 0; g < 8; g++) acc[g] = (floatx4)0.f;

    const ushort* h1 = (const ushort*)agg;

    for (int rel = 0; rel < 5; rel++) {
        __syncthreads();   // prior compute done (and sA ready on first iter)
        if (rel < 4) {
            // stage A = bf16(relu(bn(h1))) : 64 rows x 16 chunks of 8 ushorts
            #pragma unroll
            for (int p = 0; p < 4; p++) {
                int c = tid + p * 256;      // 1024 chunks
                int row = c >> 4, off = (c & 15) * 8;   // off in ushorts
                unsigned uu[4] = {0, 0, 0, 0};
                if (n0 + row < NN) {
                    uint4 v = *(const uint4*)(h1 + ((size_t)rel * NN + n0 + row) * 256 + off);
                    uu[0] = v.x; uu[1] = v.y; uu[2] = v.z; uu[3] = v.w;
                    #pragma unroll
                    for (int j = 0; j < 4; j++) {
                        int c0 = off + j * 2;
                        float v0 = bf2f((ushort)(uu[j] & 0xffffu));
                        float v1 = bf2f((ushort)(uu[j] >> 16));
                        v0 = fmaxf(fmaf(v0, sA[rel][c0], sB[rel][c0]), 0.f);
                        v1 = fmaxf(fmaf(v1, sA[rel][c0 + 1], sB[rel][c0 + 1]), 0.f);
                        uu[j] = (unsigned)f2bf(v0) | ((unsigned)f2bf(v1) << 16);
                    }
                }
                *(uint4*)&At[row * LDW + off] = make_uint4(uu[0], uu[1], uu[2], uu[3]);
            }
        } else {
            // stage A = bf16(x)
            #pragma unroll
            for (int p = 0; p < 8; p++) {
                int i4 = tid + p * 256;     // 2048 float4: 64 rows x 32
                int row = i4 >> 5;
                int c4 = (i4 & 31) * 4;
                unsigned lo = 0, hi = 0;
                if (n0 + row < NN) {
                    float4 b = *(const float4*)(x + (size_t)(n0 + row) * F + c4);
                    lo = (unsigned)f2bf(b.x) | ((unsigned)f2bf(b.y) << 16);
                    hi = (unsigned)f2bf(b.z) | ((unsigned)f2bf(b.w) << 16);
                }
                *(uint2*)&At[row * LDW + c4] = make_uint2(lo, hi);
            }
        }
        // stage Wt : 128 rows x 16 chunks of 8 ushorts
        {
            int mat = (rel < 4) ? (NREL + rel) : 8;
            const ushort* wg = Wt_g + (size_t)mat * F * F;
            #pragma unroll
            for (int p = 0; p < 8; p++) {
                int c = tid + p * 256;      // 2048 chunks
                int n = c >> 4, off = (c & 15) * 8;
                *(uint4*)&Wt[n * LDW + off] = *(const uint4*)(wg + c * 8);
            }
        }
        __syncthreads();
        const ushort* Ap = &At[(rb + m) * LDW + quad * 8];
        const ushort* Bp = &Wt[m * LDW + quad * 8];
        #pragma unroll
        for (int kk = 0; kk < 4; kk++) {
            short8 a = *(const short8*)(Ap + kk * 32);
            #pragma unroll
            for (int g = 0; g < 8; g++) {
                short8 b = *(const short8*)(Bp + g * 16 * LDW + kk * 32);
                acc[g] = __builtin_amdgcn_mfma_f32_16x16x32_bf16(a, b, acc[g], 0, 0, 0);
            }
        }
    }
    __syncthreads();

    // epilogue via LDS transpose (reuse Wt region as f32 staging: 64x128 f32 = 32 KB)
    float* Ct = (float*)Wt;
    #pragma unroll
    for (int g = 0; g < 8; g++) {
        int c = g * 16 + m;
        float bv = bself[c] + b2[0 * F + c] + b2[1 * F + c] + b2[2 * F + c] + b2[3 * F + c];
        #pragma unroll
        for (int i = 0; i < 4; i++) {
            int lrow = rb + quad * 4 + i;
            Ct[lrow * F + c] = acc[g][i] + bv;
        }
    }
    __syncthreads();
    #pragma unroll
    for (int p = 0; p < 8; p++) {
        int i4 = tid + p * 256;
        int row = i4 >> 5;
        int c4 = (i4 & 31) * 4;
        if (n0 + row < NN)
            *(float4*)(out + (size_t)(n0 + row) * F + c4) = *(const float4*)&Ct[row * F + c4];
    }
}

extern "C" void kernel_launch(void* const* d_in, const int* in_sizes, int n_in,
                              void* d_out, int out_size, void* d_ws, size_t ws_size,
                              hipStream_t stream) {
    const float* x     = (const float*)d_in[0];
    const int*   ei    = (const int*)d_in[1];
    const int*   et    = (const int*)d_in[2];
    const float* Wself = (const float*)d_in[3];
    const float* bself = (const float*)d_in[4];
    const float* W1    = (const float*)d_in[5];
    const float* b1    = (const float*)d_in[6];
    const float* gamma = (const float*)d_in[7];
    const float* beta  = (const float*)d_in[8];
    const float* W2    = (const float*)d_in[9];
    const float* b2    = (const float*)d_in[10];
    float* out = (float*)d_out;

    float* agg = (float*)d_ws;                        // [NREL, NN, F] f32 -> h1 bf16 in-place
    size_t agg_elems = (size_t)NREL * NN * F;
    float* sums  = agg + agg_elems;                   // [NREL, F]
    float* sumsq = sums + NREL * F;                   // [NREL, F]
    ushort* Wt_g = (ushort*)(sumsq + NREL * F);       // [9, F, F] bf16 transposed

    hipMemsetAsync(d_ws, 0, (agg_elems + 2 * (size_t)NREL * F) * sizeof(float), stream);

    prep_kernel<<<9, 256, 0, stream>>>(W1, W2, Wself, Wt_g);
    {
        long total = (long)NE * F;
        int grid = (int)((total + 255) / 256);
        scatter_kernel<<<grid, 256, 0, stream>>>(x, ei, et, agg);
    }
    {
        dim3 grid((NN + ROWS - 1) / ROWS, NREL);
        gemm1_kernel<<<grid, 256, 0, stream>>>(x, Wt_g, b1, agg, sums, sumsq);
    }
    {
        int grid = (NN + ROWS - 1) / ROWS;
        gemm2_kernel<<<grid, 256, 0, stream>>>(x, agg, Wt_g, b2, bself, gamma, beta,
                                               sums, sumsq, out);
    }
}

// Round 4
// 361.721 us; speedup vs baseline: 2.1701x; 1.6332x over previous
//
#include <hip/hip_runtime.h>

#define NN 50000
#define NE 800000
#define F 128
#define NREL 4
#define RN (NREL * NN)          // number of segments
#define NB 196                  // scan blocks: ceil(RN / 1024)
#define BN_EPS 1e-5f
#define ROWS 64                 // rows per block tile
#define LDW 136                 // padded LDS row stride in bf16 elems

typedef __attribute__((ext_vector_type(8))) short short8;
typedef __attribute__((ext_vector_type(4))) float floatx4;

__device__ __forceinline__ ushort f2bf(float f) {
    union { float f; unsigned u; } v; v.f = f;
    unsigned r = v.u + 0x7fffu + ((v.u >> 16) & 1u);
    return (ushort)(r >> 16);
}
__device__ __forceinline__ float bf2f(ushort h) {
    union { unsigned u; float f; } v; v.u = ((unsigned)h) << 16;
    return v.f;
}

// ---------------- histogram: counts[rel*NN+dst]++ ----------------
__global__ __launch_bounds__(256) void hist_kernel(
    const int* __restrict__ ei, const int* __restrict__ et, int* __restrict__ counts)
{
    int e = blockIdx.x * 256 + threadIdx.x;
    if (e >= NE) return;
    atomicAdd(&counts[et[e] * NN + ei[NE + e]], 1);
}

// ---------------- scan stage 1: per-block (1024 elems) local exclusive scan ----------------
__global__ __launch_bounds__(256) void scan1_kernel(
    const int* __restrict__ counts, int* __restrict__ rowptr, int* __restrict__ bsum)
{
    __shared__ int wsum[4];
    const int tid = threadIdx.x;
    const int base = blockIdx.x * 1024 + tid * 4;
    int c[4];
    #pragma unroll
    for (int j = 0; j < 4; j++) c[j] = (base + j < RN) ? counts[base + j] : 0;
    int tsum = c[0] + c[1] + c[2] + c[3];
    const int lane = tid & 63, wv = tid >> 6;
    int s = tsum;
    #pragma unroll
    for (int d = 1; d < 64; d <<= 1) { int t = __shfl_up(s, d); if (lane >= d) s += t; }
    if (lane == 63) wsum[wv] = s;
    __syncthreads();
    int wave_off = 0;
    #pragma unroll
    for (int w = 0; w < 4; w++) if (w < wv) wave_off += wsum[w];
    int run = wave_off + s - tsum;
    #pragma unroll
    for (int j = 0; j < 4; j++) {
        if (base + j < RN) rowptr[base + j] = run;
        run += c[j];
    }
    if (tid == 0) bsum[blockIdx.x] = wsum[0] + wsum[1] + wsum[2] + wsum[3];
}

// ---------------- scan stage 2: exclusive scan of NB block sums ----------------
__global__ __launch_bounds__(256) void scan2_kernel(
    const int* __restrict__ bsum, int* __restrict__ boff, int* __restrict__ rowptr)
{
    __shared__ int wsum[4];
    const int tid = threadIdx.x;
    int v = (tid < NB) ? bsum[tid] : 0;
    const int lane = tid & 63, wv = tid >> 6;
    int s = v;
    #pragma unroll
    for (int d = 1; d < 64; d <<= 1) { int t = __shfl_up(s, d); if (lane >= d) s += t; }
    if (lane == 63) wsum[wv] = s;
    __syncthreads();
    int wave_off = 0;
    #pragma unroll
    for (int w = 0; w < 4; w++) if (w < wv) wave_off += wsum[w];
    if (tid < NB) boff[tid] = wave_off + s - v;
    if (tid == 0) rowptr[RN] = wsum[0] + wsum[1] + wsum[2] + wsum[3];   // == NE
}

// ---------------- scan stage 3: add block offsets; init cursor ----------------
__global__ __launch_bounds__(256) void scan3_kernel(
    int* __restrict__ rowptr, const int* __restrict__ boff, int* __restrict__ cursor)
{
    const int base = blockIdx.x * 1024 + threadIdx.x * 4;
    const int off = boff[blockIdx.x];
    #pragma unroll
    for (int j = 0; j < 4; j++) {
        int idx = base + j;
        if (idx < RN) { int v = rowptr[idx] + off; rowptr[idx] = v; cursor[idx] = v; }
    }
}

// ---------------- reorder: sorted_src[pos] = src, pos = cursor[key]++ ----------------
__global__ __launch_bounds__(256) void reorder_kernel(
    const int* __restrict__ ei, const int* __restrict__ et,
    int* __restrict__ cursor, int* __restrict__ sorted_src)
{
    int e = blockIdx.x * 256 + threadIdx.x;
    if (e >= NE) return;
    int key = et[e] * NN + ei[NE + e];
    int pos = atomicAdd(&cursor[key], 1);
    sorted_src[pos] = ei[e];
}

// ---------------- prep: weights -> bf16 transposed Wt_g[mat][n][k] ----------------
// mats 0..3 = W1[r], 4..7 = W2[r], 8 = Wself
__global__ __launch_bounds__(256) void prep_kernel(
    const float* __restrict__ W1, const float* __restrict__ W2,
    const float* __restrict__ Wself, ushort* __restrict__ Wt_g)
{
    __shared__ ushort Lt[F * F];   // 32 KB
    int m = blockIdx.x;
    const float* src = (m < 4) ? (W1 + (size_t)m * F * F)
                     : (m < 8) ? (W2 + (size_t)(m - 4) * F * F)
                               : Wself;
    int tid = threadIdx.x;
    #pragma unroll
    for (int p = 0; p < 16; p++) {
        int i4 = tid + p * 256;
        int k = i4 >> 5;
        int n4 = (i4 & 31) * 4;
        float4 v = *(const float4*)(src + (size_t)k * F + n4);
        Lt[(n4 + 0) * F + k] = f2bf(v.x);
        Lt[(n4 + 1) * F + k] = f2bf(v.y);
        Lt[(n4 + 2) * F + k] = f2bf(v.z);
        Lt[(n4 + 3) * F + k] = f2bf(v.w);
    }
    __syncthreads();
    #pragma unroll
    for (int p = 0; p < 8; p++) {
        int c = tid + p * 256;
        *(uint4*)(Wt_g + (size_t)m * F * F + c * 8) = *(const uint4*)&Lt[c * 8];
    }
}

// ------ GEMM1 (fused gather): h1 = bf16((x[dst]+sum x[src]) @ W1[r] + b1[r]), BN stats ------
__global__ __launch_bounds__(256) void gemm1_kernel(
    const float* __restrict__ x, const int* __restrict__ rowptr,
    const int* __restrict__ sorted_src, const ushort* __restrict__ Wt_g,
    const float* __restrict__ b1, ushort* __restrict__ h1,
    float* __restrict__ sums, float* __restrict__ sumsq)
{
    __shared__ __attribute__((aligned(16))) ushort At[ROWS * LDW];  // 17 KB
    __shared__ __attribute__((aligned(16))) ushort Wt[F * LDW];     // 34.8 KB
    __shared__ float csum[F], csq[F];

    const int tid = threadIdx.x;
    const int r = blockIdx.y;
    const int n0 = blockIdx.x * ROWS;

    if (tid < F) { csum[tid] = 0.f; csq[tid] = 0.f; }

    // ---- stage A = bf16(x[n] + sum_{e in seg(r,n)} x[src_e]) : 4 threads/row, 32 feats each
    {
        const int row = tid >> 2;
        const int fc = (tid & 3) * 32;
        const int n = n0 + row;
        float4 acc[8];
        if (n < NN) {
            const float* xr = x + (size_t)n * F + fc;
            #pragma unroll
            for (int j = 0; j < 8; j++) acc[j] = *(const float4*)(xr + j * 4);
            int e0 = rowptr[r * NN + n];
            int e1 = rowptr[r * NN + n + 1];
            for (int e = e0; e < e1; ++e) {
                int src = sorted_src[e];
                const float* xs = x + (size_t)src * F + fc;
                #pragma unroll
                for (int j = 0; j < 8; j++) {
                    float4 v = *(const float4*)(xs + j * 4);
                    acc[j].x += v.x; acc[j].y += v.y; acc[j].z += v.z; acc[j].w += v.w;
                }
            }
        } else {
            #pragma unroll
            for (int j = 0; j < 8; j++) acc[j] = make_float4(0.f, 0.f, 0.f, 0.f);
        }
        ushort* dst = &At[row * LDW + fc];
        #pragma unroll
        for (int j = 0; j < 8; j += 2) {
            uint4 u;
            u.x = (unsigned)f2bf(acc[j].x)     | ((unsigned)f2bf(acc[j].y) << 16);
            u.y = (unsigned)f2bf(acc[j].z)     | ((unsigned)f2bf(acc[j].w) << 16);
            u.z = (unsigned)f2bf(acc[j + 1].x) | ((unsigned)f2bf(acc[j + 1].y) << 16);
            u.w = (unsigned)f2bf(acc[j + 1].z) | ((unsigned)f2bf(acc[j + 1].w) << 16);
            *(uint4*)(dst + j * 4) = u;
        }
    }
    // ---- stage Wt (bf16 [n][k]) : 128 rows x 16 chunks of 8 ushorts
    {
        const ushort* wg = Wt_g + (size_t)r * F * F;
        #pragma unroll
        for (int p = 0; p < 8; p++) {
            int c = tid + p * 256;
            int n = c >> 4, off = (c & 15) * 8;
            *(uint4*)&Wt[n * LDW + off] = *(const uint4*)(wg + c * 8);
        }
    }
    __syncthreads();

    const int lane = tid & 63, w = tid >> 6;
    const int m = lane & 15, quad = lane >> 4;
    const int rb = w * 16;
    floatx4 acc[8];
    #pragma unroll
    for (int g = 0; g < 8; g++) acc[g] = (floatx4)0.f;

    const ushort* Ap = &At[(rb + m) * LDW + quad * 8];
    const ushort* Bp = &Wt[m * LDW + quad * 8];
    #pragma unroll
    for (int kk = 0; kk < 4; kk++) {
        short8 a = *(const short8*)(Ap + kk * 32);
        #pragma unroll
        for (int g = 0; g < 8; g++) {
            short8 b = *(const short8*)(Bp + g * 16 * LDW + kk * 32);
            acc[g] = __builtin_amdgcn_mfma_f32_16x16x32_bf16(a, b, acc[g], 0, 0, 0);
        }
    }
    __syncthreads();   // all waves done reading At/Wt

    // epilogue: bias, BN partial sums, bf16 result into At (stride LDW)
    #pragma unroll
    for (int g = 0; g < 8; g++) {
        int c = g * 16 + m;
        float bv = b1[r * F + c];
        float ls = 0.f, lq = 0.f;
        #pragma unroll
        for (int i = 0; i < 4; i++) {
            int lrow = rb + quad * 4 + i;
            float v = acc[g][i] + bv;
            At[lrow * LDW + c] = f2bf(v);
            if (n0 + lrow < NN) { ls += v; lq += v * v; }
        }
        atomicAdd(&csum[c], ls);
        atomicAdd(&csq[c], lq);
    }
    __syncthreads();

    // h1 bf16 out: 64 rows x 16 chunks of 8 ushorts, stride 128
    #pragma unroll
    for (int p = 0; p < 4; p++) {
        int c = tid + p * 256;
        int row = c >> 4, off = (c & 15) * 8;
        if (n0 + row < NN)
            *(uint4*)(h1 + ((size_t)r * NN + n0 + row) * F + off) =
                *(const uint4*)&At[row * LDW + off];
    }
    if (tid < F) {
        atomicAdd(&sums[r * F + tid], csum[tid]);
        atomicAdd(&sumsq[r * F + tid], csq[tid]);
    }
}

// ------- GEMM2: out = x@Wself + bself + sum_r relu(bn(h1_r))@W2[r] + b2[r] -------
__global__ __launch_bounds__(256) void gemm2_kernel(
    const float* __restrict__ x, const ushort* __restrict__ h1,
    const ushort* __restrict__ Wt_g,
    const float* __restrict__ b2, const float* __restrict__ bself,
    const float* __restrict__ gamma, const float* __restrict__ beta,
    const float* __restrict__ sums, const float* __restrict__ sumsq,
    float* __restrict__ out)
{
    __shared__ __attribute__((aligned(16))) ushort At[ROWS * LDW];
    __shared__ __attribute__((aligned(16))) ushort Wt[F * LDW];
    __shared__ float sA[NREL][F], sB[NREL][F];

    const int tid = threadIdx.x;
    const int n0 = blockIdx.x * ROWS;

    if (tid < F) {
        #pragma unroll
        for (int r = 0; r < NREL; r++) {
            float mean = sums[r * F + tid] * (1.0f / NN);
            float var = sumsq[r * F + tid] * (1.0f / NN) - mean * mean;
            float g = gamma[r * F + tid] * rsqrtf(var + BN_EPS);
            sA[r][tid] = g;
            sB[r][tid] = beta[r * F + tid] - mean * g;
        }
    }

    const int lane = tid & 63, w = tid >> 6;
    const int m = lane & 15, quad = lane >> 4;
    const int rb = w * 16;
    floatx4 acc[8];
    #pragma unroll
    for (int g = 0; g < 8; g++) acc[g] = (floatx4)0.f;

    for (int rel = 0; rel < 5; rel++) {
        __syncthreads();   // prior compute done (and sA ready on first iter)
        if (rel < 4) {
            // stage A = bf16(relu(bn(h1))) : 64 rows x 16 chunks of 8 ushorts
            #pragma unroll
            for (int p = 0; p < 4; p++) {
                int c = tid + p * 256;
                int row = c >> 4, off = (c & 15) * 8;
                unsigned uu[4] = {0, 0, 0, 0};
                if (n0 + row < NN) {
                    uint4 v = *(const uint4*)(h1 + ((size_t)rel * NN + n0 + row) * F + off);
                    uu[0] = v.x; uu[1] = v.y; uu[2] = v.z; uu[3] = v.w;
                    #pragma unroll
                    for (int j = 0; j < 4; j++) {
                        int c0 = off + j * 2;
                        float v0 = bf2f((ushort)(uu[j] & 0xffffu));
                        float v1 = bf2f((ushort)(uu[j] >> 16));
                        v0 = fmaxf(fmaf(v0, sA[rel][c0], sB[rel][c0]), 0.f);
                        v1 = fmaxf(fmaf(v1, sA[rel][c0 + 1], sB[rel][c0 + 1]), 0.f);
                        uu[j] = (unsigned)f2bf(v0) | ((unsigned)f2bf(v1) << 16);
                    }
                }
                *(uint4*)&At[row * LDW + off] = make_uint4(uu[0], uu[1], uu[2], uu[3]);
            }
        } else {
            // stage A = bf16(x)
            #pragma unroll
            for (int p = 0; p < 8; p++) {
                int i4 = tid + p * 256;
                int row = i4 >> 5;
                int c4 = (i4 & 31) * 4;
                unsigned lo = 0, hi = 0;
                if (n0 + row < NN) {
                    float4 b = *(const float4*)(x + (size_t)(n0 + row) * F + c4);
                    lo = (unsigned)f2bf(b.x) | ((unsigned)f2bf(b.y) << 16);
                    hi = (unsigned)f2bf(b.z) | ((unsigned)f2bf(b.w) << 16);
                }
                *(uint2*)&At[row * LDW + c4] = make_uint2(lo, hi);
            }
        }
        // stage Wt
        {
            int mat = (rel < 4) ? (NREL + rel) : 8;
            const ushort* wg = Wt_g + (size_t)mat * F * F;
            #pragma unroll
            for (int p = 0; p < 8; p++) {
                int c = tid + p * 256;
                int n = c >> 4, off = (c & 15) * 8;
                *(uint4*)&Wt[n * LDW + off] = *(const uint4*)(wg + c * 8);
            }
        }
        __syncthreads();
        const ushort* Ap = &At[(rb + m) * LDW + quad * 8];
        const ushort* Bp = &Wt[m * LDW + quad * 8];
        #pragma unroll
        for (int kk = 0; kk < 4; kk++) {
            short8 a = *(const short8*)(Ap + kk * 32);
            #pragma unroll
            for (int g = 0; g < 8; g++) {
                short8 b = *(const short8*)(Bp + g * 16 * LDW + kk * 32);
                acc[g] = __builtin_amdgcn_mfma_f32_16x16x32_bf16(a, b, acc[g], 0, 0, 0);
            }
        }
    }
    __syncthreads();

    // epilogue via LDS transpose (reuse Wt region as f32 staging: 64x128 f32 = 32 KB)
    float* Ct = (float*)Wt;
    #pragma unroll
    for (int g = 0; g < 8; g++) {
        int c = g * 16 + m;
        float bv = bself[c] + b2[0 * F + c] + b2[1 * F + c] + b2[2 * F + c] + b2[3 * F + c];
        #pragma unroll
        for (int i = 0; i < 4; i++) {
            int lrow = rb + quad * 4 + i;
            Ct[lrow * F + c] = acc[g][i] + bv;
        }
    }
    __syncthreads();
    #pragma unroll
    for (int p = 0; p < 8; p++) {
        int i4 = tid + p * 256;
        int row = i4 >> 5;
        int c4 = (i4 & 31) * 4;
        if (n0 + row < NN)
            *(float4*)(out + (size_t)(n0 + row) * F + c4) = *(const float4*)&Ct[row * F + c4];
    }
}

extern "C" void kernel_launch(void* const* d_in, const int* in_sizes, int n_in,
                              void* d_out, int out_size, void* d_ws, size_t ws_size,
                              hipStream_t stream) {
    const float* x     = (const float*)d_in[0];
    const int*   ei    = (const int*)d_in[1];
    const int*   et    = (const int*)d_in[2];
    const float* Wself = (const float*)d_in[3];
    const float* bself = (const float*)d_in[4];
    const float* W1    = (const float*)d_in[5];
    const float* b1    = (const float*)d_in[6];
    const float* gamma = (const float*)d_in[7];
    const float* beta  = (const float*)d_in[8];
    const float* W2    = (const float*)d_in[9];
    const float* b2    = (const float*)d_in[10];
    float* out = (float*)d_out;

    // workspace layout (16B alignment maintained)
    ushort* h1   = (ushort*)d_ws;                       // [4, NN, 128] bf16 = 51.2 MB
    ushort* Wt_g = h1 + (size_t)NREL * NN * F;          // [9, 128, 128] bf16
    float*  sums  = (float*)(Wt_g + 9 * F * F);         // [4, 128]
    float*  sumsq = sums + NREL * F;                    // [4, 128]
    int* counts     = (int*)(sumsq + NREL * F);         // [RN]
    int* rowptr     = counts + RN;                      // [RN+1]
    int* cursor     = rowptr + RN + 1;                  // [RN]
    int* sorted_src = cursor + RN;                      // [NE]
    int* bsum       = sorted_src + NE;                  // [256]
    int* boff       = bsum + 256;                       // [256]

    // zero: sums + sumsq + counts (contiguous)
    hipMemsetAsync(sums, 0, (2 * (size_t)NREL * F + RN) * sizeof(float), stream);

    prep_kernel<<<9, 256, 0, stream>>>(W1, W2, Wself, Wt_g);
    hist_kernel<<<(NE + 255) / 256, 256, 0, stream>>>(ei, et, counts);
    scan1_kernel<<<NB, 256, 0, stream>>>(counts, rowptr, bsum);
    scan2_kernel<<<1, 256, 0, stream>>>(bsum, boff, rowptr);
    scan3_kernel<<<NB, 256, 0, stream>>>(rowptr, boff, cursor);
    reorder_kernel<<<(NE + 255) / 256, 256, 0, stream>>>(ei, et, cursor, sorted_src);
    {
        dim3 grid((NN + ROWS - 1) / ROWS, NREL);
        gemm1_kernel<<<grid, 256, 0, stream>>>(x, rowptr, sorted_src, Wt_g, b1,
                                               h1, sums, sumsq);
    }
    {
        int grid = (NN + ROWS - 1) / ROWS;
        gemm2_kernel<<<grid, 256, 0, stream>>>(x, h1, Wt_g, b2, bself, gamma, beta,
                                               sums, sumsq, out);
    }
}